// Round 3
// baseline (400.321 us; speedup 1.0000x reference)
//
#include <hip/hip_runtime.h>
#include <hip/hip_bf16.h>
#include <math.h>

#define B_  8
#define C_  64
#define O_  64
#define H_  128
#define W_  128
#define HW_ (H_ * W_)

typedef __attribute__((ext_vector_type(8))) short bf16x8;
typedef __attribute__((ext_vector_type(4))) float f32x4;

__device__ __forceinline__ short f2bf(float f) {
    __hip_bfloat16 h = __float2bfloat16(f);
    return *reinterpret_cast<short*>(&h);
}

// ---------------------------------------------------------------------------
// Prep: bf16 weight layouts for MFMA A-operands (K = kt*64 + c).
//   wbf  [64 o][9 kt][64 c]           (deform)
//   wzbf [32 m][576 k]  rows >=18 = 0 (offset conv, input z)
//   wxbf [16 m][576 k]  rows >= 9 = 0 (mask   conv, input x)
// ---------------------------------------------------------------------------
__global__ void prep_weights(const float* __restrict__ w_off,
                             const float* __restrict__ w_mod,
                             const float* __restrict__ w_reg,
                             short* __restrict__ wbf,
                             short* __restrict__ wzbf,
                             short* __restrict__ wxbf) {
    int t = blockIdx.x * blockDim.x + threadIdx.x;
    if (t < 36864) {
        int o = t / 576, r = t % 576, kt = r / 64, c = r % 64;
        wbf[t] = f2bf(w_reg[o * 576 + c * 9 + kt]);
    }
    if (t < 18432) {
        int m = t / 576, r = t % 576, kt = r / 64, c = r % 64;
        wzbf[t] = (m < 18) ? f2bf(w_off[m * 576 + c * 9 + kt]) : (short)0;
    }
    if (t < 9216) {
        int m = t / 576, r = t % 576, kt = r / 64, c = r % 64;
        wxbf[t] = (m < 9) ? f2bf(w_mod[m * 576 + c * 9 + kt]) : (short)0;
    }
}

// swizzled LDS slot for (n, k-group): 2-way bank access on b128 read & write
__device__ __forceinline__ int swz(int n, int g) {
    return (g ^ ((n >> 1) ^ (n >> 4))) & 3;
}

// ---------------------------------------------------------------------------
// Conv via MFMA: off[18 ch from z] and mask[9 ch from x], 3x3 pad 1.
// GEMM: [M=32|16 padded][K=576] x [K=576][N=64 pixels], K = kt*64 + c.
// Per K-step (32): each thread stages 8 z-samples + 8 x-samples (shifted
// window loads) into swizzled LDS tiles; 12 MFMA frags spread 3 per wave.
// ---------------------------------------------------------------------------
__global__ __launch_bounds__(256) void conv_mfma(
    const float* __restrict__ x, const float* __restrict__ z,
    const short* __restrict__ wzbf, const short* __restrict__ wxbf,
    const float* __restrict__ b_off, const float* __restrict__ b_mod,
    float* __restrict__ off_out,   // [B][18][H][W]
    float* __restrict__ mask_out)  // [B][ 9][H][W]
{
    __shared__ __align__(16) short zt[64 * 32];
    __shared__ __align__(16) short xt[64 * 32];

    const int tid = threadIdx.x;
    const int lane = tid & 63;
    const int wv = tid >> 6;
    const int l15 = lane & 15;
    const int g = lane >> 4;

    const int p0 = blockIdx.x * 64;
    const int b = p0 / HW_;
    const int pix0 = p0 % HW_;
    const int ho = pix0 / W_;
    const int wx0 = pix0 % W_;

    const float* zb = z + (size_t)b * C_ * HW_;
    const float* xb = x + (size_t)b * C_ * HW_;

    f32x4 acc0 = {0.f, 0.f, 0.f, 0.f}, acc1 = acc0, acc2 = acc0;

    const int n = lane;
    const int slotw = swz(n, wv);

#pragma unroll 1
    for (int step = 0; step < 18; ++step) {
        const int kt = step >> 1, chalf = step & 1;
        const int iy = ho + kt / 3 - 1;
        const int ix = wx0 + n + kt % 3 - 1;
        const bool v = (iy >= 0) && (iy < H_) && (ix >= 0) && (ix < W_);
        const int src = iy * W_ + ix;
        const int cbase = chalf * 32 + wv * 8;

        __syncthreads();  // WAR: previous step's B-frag reads done
        {
            const float* zp = zb + (size_t)cbase * HW_;
            const float* xp = xb + (size_t)cbase * HW_;
            bf16x8 zv, xv;
#pragma unroll
            for (int cc = 0; cc < 8; ++cc) {
                float a = v ? zp[src] : 0.f;
                float bb = v ? xp[src] : 0.f;
                zv[cc] = f2bf(a);
                xv[cc] = f2bf(bb);
                zp += HW_;
                xp += HW_;
            }
            *(bf16x8*)&zt[n * 32 + slotw * 8] = zv;
            *(bf16x8*)&xt[n * 32 + slotw * 8] = xv;
        }
        const int koff = step * 32 + g * 8;
        bf16x8 az0 = *(const bf16x8*)(wzbf + (size_t)l15 * 576 + koff);
        bf16x8 az1 = *(const bf16x8*)(wzbf + (size_t)(16 + l15) * 576 + koff);
        bf16x8 ax0 = *(const bf16x8*)(wxbf + (size_t)l15 * 576 + koff);
        __syncthreads();  // RAW: samples visible

#pragma unroll
        for (int i = 0; i < 3; ++i) {
            const int fid = wv * 3 + i;      // 0..11
            const int ms = fid >> 2;         // 0,1 = z-GEMM; 2 = x-GEMM
            const int nf = fid & 3;
            const int n2 = nf * 16 + l15;
            const short* bt = (ms == 2) ? xt : zt;
            bf16x8 bv = *(const bf16x8*)&bt[n2 * 32 + swz(n2, g) * 8];
            bf16x8 av = (ms == 0) ? az0 : ((ms == 1) ? az1 : ax0);
            f32x4 cc = (i == 0) ? acc0 : ((i == 1) ? acc1 : acc2);
            cc = __builtin_amdgcn_mfma_f32_16x16x32_bf16(av, bv, cc, 0, 0, 0);
            if (i == 0) acc0 = cc; else if (i == 1) acc1 = cc; else acc2 = cc;
        }
    }

    // epilogue: D row = g*4+r, col = l15
#pragma unroll
    for (int i = 0; i < 3; ++i) {
        const int fid = wv * 3 + i;
        const int ms = fid >> 2;
        const int nf = fid & 3;
        const int pixe = pix0 + nf * 16 + l15;
        f32x4 cc = (i == 0) ? acc0 : ((i == 1) ? acc1 : acc2);
#pragma unroll
        for (int r = 0; r < 4; ++r) {
            const int row = g * 4 + r;
            if (ms < 2) {
                const int j = ms * 16 + row;
                if (j < 18)
                    off_out[((size_t)b * 18 + j) * HW_ + pixe] = cc[r] + b_off[j];
            } else {
                const int j = row;
                if (j < 9) {
                    float s = cc[r] + b_mod[j];
                    mask_out[((size_t)b * 9 + j) * HW_ + pixe] =
                        2.f / (1.f + expf(-s));
                }
            }
        }
    }
}

// ---------------------------------------------------------------------------
// Deform via MFMA: GEMM [M=64 out-ch][K=576] x [K=576][N=64 pixels].
// Per K-step: each thread bilinearly samples 8 channels of its own pixel
// (params recomputed per tap from off/mask buffers), writes bf16x8 to
// swizzled LDS; each wave owns a 16-row M-slice and 4 N-frags.
// ---------------------------------------------------------------------------
__global__ __launch_bounds__(256) void deform_mfma(
    const float* __restrict__ x,
    const float* __restrict__ off_in, const float* __restrict__ mask_in,
    const short* __restrict__ wbf,    // [64 o][9 kt][64 c]
    float* __restrict__ out)
{
    __shared__ __align__(16) short btile[64 * 32];

    const int tid = threadIdx.x;
    const int lane = tid & 63;
    const int wv = tid >> 6;
    const int l15 = lane & 15;
    const int g = lane >> 4;

    const int p0 = blockIdx.x * 64;
    const int b = p0 / HW_;
    const int pix0 = p0 % HW_;
    const int ho = pix0 / W_;
    const int wx0 = pix0 % W_;

    const float* xb = x + (size_t)b * C_ * HW_;
    const int pix = pix0 + lane;

    f32x4 acc0 = {0.f, 0.f, 0.f, 0.f}, acc1 = acc0, acc2 = acc0, acc3 = acc0;

    const int n = lane;
    const int slotw = swz(n, wv);

    float w00 = 0.f, w01 = 0.f, w10 = 0.f, w11 = 0.f;
    int i00 = 0, i01 = 0, i10 = 0, i11 = 0;

#pragma unroll 1
    for (int step = 0; step < 18; ++step) {
        const int kt = step >> 1, chalf = step & 1;
        if (chalf == 0) {
            float dy = off_in[((size_t)b * 18 + 2 * kt) * HW_ + pix];
            float dx = off_in[((size_t)b * 18 + 2 * kt + 1) * HW_ + pix];
            float m  = mask_in[((size_t)b * 9 + kt) * HW_ + pix];
            float py = dy + (float)(kt / 3 + ho - 1);
            float px = dx + (float)(kt % 3 + wx0 + n - 1);
            float y0f = floorf(py), x0f = floorf(px);
            float wy1 = py - y0f, wy0 = 1.f - wy1;
            float wx1 = px - x0f, wx0w = 1.f - wx1;
            int y0 = (int)y0f, x0i = (int)x0f;
            int y1 = y0 + 1, x1 = x0i + 1;
            bool vy0 = (y0 >= 0) && (y0 < H_), vy1 = (y1 >= 0) && (y1 < H_);
            bool vx0 = (x0i >= 0) && (x0i < W_), vx1 = (x1 >= 0) && (x1 < W_);
            w00 = wy0 * wx0w * ((vy0 && vx0) ? m : 0.f);
            w01 = wy0 * wx1 * ((vy0 && vx1) ? m : 0.f);
            w10 = wy1 * wx0w * ((vy1 && vx0) ? m : 0.f);
            w11 = wy1 * wx1 * ((vy1 && vx1) ? m : 0.f);
            int y0c = min(max(y0, 0), H_ - 1), y1c = min(max(y1, 0), H_ - 1);
            int x0c = min(max(x0i, 0), W_ - 1), x1c = min(max(x1, 0), W_ - 1);
            i00 = y0c * W_ + x0c; i01 = y0c * W_ + x1c;
            i10 = y1c * W_ + x0c; i11 = y1c * W_ + x1c;
        }
        const int cbase = chalf * 32 + wv * 8;

        __syncthreads();  // WAR
        {
            const float* xc = xb + (size_t)cbase * HW_;
            bf16x8 sv;
#pragma unroll
            for (int cc = 0; cc < 8; ++cc) {
                float v = xc[i00] * w00 + xc[i01] * w01 + xc[i10] * w10 +
                          xc[i11] * w11;
                sv[cc] = f2bf(v);
                xc += HW_;
            }
            *(bf16x8*)&btile[n * 32 + slotw * 8] = sv;
        }
        const int m = wv * 16 + l15;
        bf16x8 av = *(const bf16x8*)(wbf + (size_t)m * 576 + step * 32 + g * 8);
        __syncthreads();  // RAW

#pragma unroll
        for (int fi = 0; fi < 4; ++fi) {
            const int n2 = fi * 16 + l15;
            bf16x8 bv = *(const bf16x8*)&btile[n2 * 32 + swz(n2, g) * 8];
            f32x4 cc = (fi == 0) ? acc0 : ((fi == 1) ? acc1
                        : ((fi == 2) ? acc2 : acc3));
            cc = __builtin_amdgcn_mfma_f32_16x16x32_bf16(av, bv, cc, 0, 0, 0);
            if (fi == 0) acc0 = cc; else if (fi == 1) acc1 = cc;
            else if (fi == 2) acc2 = cc; else acc3 = cc;
        }
    }

    // epilogue: o = wv*16 + g*4 + r, pixel = pix0 + fi*16 + l15
#pragma unroll
    for (int fi = 0; fi < 4; ++fi) {
        f32x4 cc = (fi == 0) ? acc0 : ((fi == 1) ? acc1
                    : ((fi == 2) ? acc2 : acc3));
#pragma unroll
        for (int r = 0; r < 4; ++r) {
            const int o = wv * 16 + g * 4 + r;
            out[((size_t)b * O_ + o) * HW_ + pix0 + fi * 16 + l15] = cc[r];
        }
    }
}

// ---------------------------------------------------------------------------
// Fallback (no workspace): fully fused fp32, slow but correct.
// ---------------------------------------------------------------------------
__global__ __launch_bounds__(256) void deform_fallback(
    const float* __restrict__ x, const float* __restrict__ z,
    const float* __restrict__ w_regp,
    const float* __restrict__ w_off, const float* __restrict__ b_off,
    const float* __restrict__ w_mod, const float* __restrict__ b_mod,
    float* __restrict__ out) {
    int p = blockIdx.x * blockDim.x + threadIdx.x;
    if (p >= B_ * HW_) return;
    int wo = p % W_;
    int ho = (p / W_) % H_;
    int b  = p / HW_;
    int pix = ho * W_ + wo;

    const float* xb = x + (size_t)b * C_ * HW_;

    float accO[18], accM[9];
#pragma unroll
    for (int j = 0; j < 18; ++j) accO[j] = b_off[j];
#pragma unroll
    for (int j = 0; j < 9; ++j) accM[j] = b_mod[j];
    const float* zb = z + (size_t)b * C_ * HW_;
#pragma unroll 1
    for (int c = 0; c < C_; ++c) {
        const float* zc = zb + c * HW_;
        const float* xc = xb + c * HW_;
#pragma unroll
        for (int ky = 0; ky < 3; ++ky) {
            int iy = ho + ky - 1;
            bool vy = (iy >= 0) && (iy < H_);
#pragma unroll
            for (int kx = 0; kx < 3; ++kx) {
                int ix = wo + kx - 1;
                bool v = vy && (ix >= 0) && (ix < W_);
                int k = ky * 3 + kx;
                float zv = v ? zc[iy * W_ + ix] : 0.f;
                float xv = v ? xc[iy * W_ + ix] : 0.f;
#pragma unroll
                for (int j = 0; j < 18; ++j)
                    accO[j] = fmaf(zv, w_off[j * 576 + c * 9 + k], accO[j]);
#pragma unroll
                for (int j = 0; j < 9; ++j)
                    accM[j] = fmaf(xv, w_mod[j * 576 + c * 9 + k], accM[j]);
            }
        }
    }
    float mv[9];
#pragma unroll
    for (int j = 0; j < 9; ++j) mv[j] = 2.f / (1.f + expf(-accM[j]));

    float acc[64];
#pragma unroll
    for (int o = 0; o < 64; ++o) acc[o] = 0.f;

#pragma unroll 1
    for (int k = 0; k < 9; ++k) {
        float dy = accO[2 * k], dx = accO[2 * k + 1], m = mv[k];
        float py = dy + (float)(k / 3 + ho - 1);
        float px = dx + (float)(k % 3 + wo - 1);
        float y0f = floorf(py), x0f = floorf(px);
        float wy1 = py - y0f, wy0 = 1.f - wy1;
        float wx1 = px - x0f, wx0 = 1.f - wx1;
        int y0 = (int)y0f, x0i = (int)x0f;
        int y1 = y0 + 1, x1 = x0i + 1;
        bool vy0 = (y0 >= 0) && (y0 < H_), vy1 = (y1 >= 0) && (y1 < H_);
        bool vx0 = (x0i >= 0) && (x0i < W_), vx1 = (x1 >= 0) && (x1 < W_);
        float w00 = wy0 * wx0 * ((vy0 && vx0) ? m : 0.f);
        float w01 = wy0 * wx1 * ((vy0 && vx1) ? m : 0.f);
        float w10 = wy1 * wx0 * ((vy1 && vx0) ? m : 0.f);
        float w11 = wy1 * wx1 * ((vy1 && vx1) ? m : 0.f);
        int y0c = min(max(y0, 0), H_ - 1), y1c = min(max(y1, 0), H_ - 1);
        int x0c = min(max(x0i, 0), W_ - 1), x1c = min(max(x1, 0), W_ - 1);
        int i00 = y0c * W_ + x0c, i01 = y0c * W_ + x1c;
        int i10 = y1c * W_ + x0c, i11 = y1c * W_ + x1c;
#pragma unroll 1
        for (int c = 0; c < C_; ++c) {
            const float* xc = xb + c * HW_;
            float val = xc[i00] * w00 + xc[i01] * w01 + xc[i10] * w10 +
                        xc[i11] * w11;
            const float* wr = w_regp + c * 9 + k;
#pragma unroll
            for (int o = 0; o < 64; ++o)
                acc[o] = fmaf(val, wr[o * 576], acc[o]);
        }
    }
    float* ob = out + (size_t)b * O_ * HW_ + pix;
#pragma unroll
    for (int o = 0; o < 64; ++o) ob[o * HW_] = acc[o];
}

// ---------------------------------------------------------------------------
extern "C" void kernel_launch(void* const* d_in, const int* in_sizes, int n_in,
                              void* d_out, int out_size, void* d_ws,
                              size_t ws_size, hipStream_t stream) {
    const float* x     = (const float*)d_in[0];
    const float* z     = (const float*)d_in[1];
    const float* w_off = (const float*)d_in[2];
    const float* b_off = (const float*)d_in[3];
    const float* w_mod = (const float*)d_in[4];
    const float* b_mod = (const float*)d_in[5];
    const float* w_reg = (const float*)d_in[6];
    float* out = (float*)d_out;

    // ws layout (bytes):
    //   wbf   36864 sh = 73728
    //   wzbf  18432 sh = 36864
    //   wxbf   9216 sh = 18432   -> 129024 total weights
    //   off_buf B*18*HW f32 = 9437184
    //   mask_buf B*9*HW f32 = 4718592
    const size_t need = 129024 + 9437184 + 4718592;

    const int npix = B_ * HW_;   // 131072
    const int ntile = npix / 64; // 2048

    if (ws_size >= need) {
        short* wbf  = (short*)d_ws;
        short* wzbf = wbf + 36864;
        short* wxbf = wzbf + 18432;
        float* off_buf  = (float*)((char*)d_ws + 129024);
        float* mask_buf = off_buf + (size_t)B_ * 18 * HW_;
        prep_weights<<<144, 256, 0, stream>>>(w_off, w_mod, w_reg, wbf, wzbf,
                                              wxbf);
        conv_mfma<<<ntile, 256, 0, stream>>>(x, z, wzbf, wxbf, b_off, b_mod,
                                             off_buf, mask_buf);
        deform_mfma<<<ntile, 256, 0, stream>>>(x, off_buf, mask_buf, wbf, out);
    } else {
        deform_fallback<<<(npix + 255) / 256, 256, 0, stream>>>(
            x, z, w_reg, w_off, b_off, w_mod, b_mod, out);
    }
}

// Round 4
// 197.808 us; speedup vs baseline: 2.0238x; 2.0238x over previous
//
#include <hip/hip_runtime.h>
#include <hip/hip_bf16.h>
#include <math.h>

#define B_  8
#define C_  64
#define O_  64
#define H_  128
#define W_  128
#define HW_ (H_ * W_)

typedef __attribute__((ext_vector_type(8))) short bf16x8;
typedef __attribute__((ext_vector_type(4))) float f32x4;

__device__ __forceinline__ short f2bf(float f) {
    __hip_bfloat16 h = __float2bfloat16(f);
    return *reinterpret_cast<short*>(&h);
}
__device__ __forceinline__ float bf2f(short u) {
    unsigned int v = ((unsigned int)(unsigned short)u) << 16;
    return __uint_as_float(v);
}

// swizzled LDS slot for (n, k-group): spreads b128 banks
__device__ __forceinline__ int swz(int n, int g) {
    return (g ^ ((n >> 1) ^ (n >> 4))) & 3;
}

// ---------------------------------------------------------------------------
// Prep 1: bf16 weight layouts for MFMA A-operands (K = kt*64 + c).
//   wbf  [64 o][9 kt][64 c]           (deform)
//   wzbf [32 m][576 k]  rows >=18 = 0 (offset conv, input z)
//   wxbf [16 m][576 k]  rows >= 9 = 0 (mask   conv, input x)
// ---------------------------------------------------------------------------
__global__ void prep_weights(const float* __restrict__ w_off,
                             const float* __restrict__ w_mod,
                             const float* __restrict__ w_reg,
                             short* __restrict__ wbf,
                             short* __restrict__ wzbf,
                             short* __restrict__ wxbf) {
    int t = blockIdx.x * blockDim.x + threadIdx.x;
    if (t < 36864) {
        int o = t / 576, r = t % 576, kt = r / 64, c = r % 64;
        wbf[t] = f2bf(w_reg[o * 576 + c * 9 + kt]);
    }
    if (t < 18432) {
        int m = t / 576, r = t % 576, kt = r / 64, c = r % 64;
        wzbf[t] = (m < 18) ? f2bf(w_off[m * 576 + c * 9 + kt]) : (short)0;
    }
    if (t < 9216) {
        int m = t / 576, r = t % 576, kt = r / 64, c = r % 64;
        wxbf[t] = (m < 9) ? f2bf(w_mod[m * 576 + c * 9 + kt]) : (short)0;
    }
}

// ---------------------------------------------------------------------------
// Prep 2: NCHW fp32 -> NHWC bf16 for x and z. Block = (b, y, 64-px xseg):
// LDS-transposed so both global read and write are coalesced.
// ---------------------------------------------------------------------------
__global__ __launch_bounds__(256) void to_nhwc(
    const float* __restrict__ x, const float* __restrict__ z,
    unsigned short* __restrict__ xn, unsigned short* __restrict__ zn) {
    __shared__ float t[64 * 65];
    const int bid = blockIdx.x;
    const int xseg = bid & 1;
    const int y = (bid >> 1) & 127;
    const int b = bid >> 8;

#pragma unroll
    for (int arr = 0; arr < 2; ++arr) {
        const float* src = arr ? z : x;
        unsigned short* dst = arr ? zn : xn;
#pragma unroll
        for (int i = 0; i < 16; ++i) {
            int e = threadIdx.x + i * 256;   // 0..4095
            int c = e >> 6, px = e & 63;
            t[px * 65 + c] =
                src[((size_t)(b * 64 + c) * H_ + y) * W_ + xseg * 64 + px];
        }
        __syncthreads();
#pragma unroll
        for (int i = 0; i < 2; ++i) {
            int j = threadIdx.x + i * 256;   // 0..511
            int px = j >> 3, q = j & 7;
            bf16x8 v;
#pragma unroll
            for (int jj = 0; jj < 8; ++jj)
                v[jj] = f2bf(t[px * 65 + q * 8 + jj]);
            *(bf16x8*)(dst +
                       ((size_t)((b * H_ + y) * W_ + xseg * 64 + px)) * 64 +
                       q * 8) = v;
        }
        __syncthreads();
    }
}

// ---------------------------------------------------------------------------
// Conv via MFMA, halo-staged: off[18 from z], mask[9 from x], 3x3 pad 1.
// Block = 64-pixel row segment. Stage 3x66x64ch halos of z and x in LDS
// ONCE (granule-swizzled), single sync, then 18 K-steps x 12 MFMA with no
// further syncs. Each global element read exactly once per block.
// ---------------------------------------------------------------------------
__global__ __launch_bounds__(256) void conv_mfma2(
    const unsigned short* __restrict__ zn, const unsigned short* __restrict__ xn,
    const short* __restrict__ wzbf, const short* __restrict__ wxbf,
    const float* __restrict__ b_off, const float* __restrict__ b_mod,
    float* __restrict__ off_out,   // [B][18][H][W]
    float* __restrict__ mask_out)  // [B][ 9][H][W]
{
    __shared__ __align__(16) unsigned short zh[198 * 64];
    __shared__ __align__(16) unsigned short xh[198 * 64];

    const int tid = threadIdx.x;
    const int lane = tid & 63;
    const int wv = tid >> 6;
    const int l15 = lane & 15;
    const int g = lane >> 4;

    const int p0 = blockIdx.x * 64;
    const int b = p0 / HW_;
    const int pix0 = p0 % HW_;
    const int ho = pix0 / W_;
    const int wx0 = pix0 % W_;

    // ---- stage both halos (each element loaded once) ----
    for (int t = tid; t < 3168; t += 256) {
        const int arr = (t >= 1584) ? 1 : 0;
        const int t2 = t - arr * 1584;
        const int p = t2 >> 3, q = t2 & 7;
        const int r = p / 66, cc = p - r * 66;
        const int iy = ho + r - 1, ix = wx0 + cc - 1;
        const bool valid = (iy >= 0) && (iy < H_) && (ix >= 0) && (ix < W_);
        bf16x8 v;
#pragma unroll
        for (int jj = 0; jj < 8; ++jj) v[jj] = 0;
        if (valid) {
            const unsigned short* src = arr ? xn : zn;
            v = *(const bf16x8*)(src +
                                 ((size_t)((b * H_ + iy) * W_ + ix)) * 64 +
                                 q * 8);
        }
        unsigned short* dst = arr ? xh : zh;
        *(bf16x8*)&dst[p * 64 + ((q ^ (p & 7)) * 8)] = v;
    }
    __syncthreads();

    f32x4 acc0 = {0.f, 0.f, 0.f, 0.f}, acc1 = acc0, acc2 = acc0;

#pragma unroll 1
    for (int step = 0; step < 18; ++step) {
        const int kt = step >> 1, chalf = step & 1;
        const int ky = kt / 3, kx = kt - ky * 3;
        const int koff = step * 32 + g * 8;
        bf16x8 az0 = *(const bf16x8*)(wzbf + (size_t)l15 * 576 + koff);
        bf16x8 az1 = *(const bf16x8*)(wzbf + (size_t)(16 + l15) * 576 + koff);
        bf16x8 ax0 = *(const bf16x8*)(wxbf + (size_t)l15 * 576 + koff);

#pragma unroll
        for (int i = 0; i < 3; ++i) {
            const int fid = wv * 3 + i;      // 0..11
            const int ms = fid >> 2;         // 0,1 = z-GEMM; 2 = x-GEMM
            const int nf = fid & 3;
            const int n2 = nf * 16 + l15;
            const int p = ky * 66 + n2 + kx;
            const int gq = (chalf * 4 + g) ^ (p & 7);
            const unsigned short* bt = (ms == 2) ? xh : zh;
            bf16x8 bv = *(const bf16x8*)&bt[p * 64 + gq * 8];
            bf16x8 av = (ms == 0) ? az0 : ((ms == 1) ? az1 : ax0);
            f32x4 cc = (i == 0) ? acc0 : ((i == 1) ? acc1 : acc2);
            cc = __builtin_amdgcn_mfma_f32_16x16x32_bf16(av, bv, cc, 0, 0, 0);
            if (i == 0) acc0 = cc; else if (i == 1) acc1 = cc; else acc2 = cc;
        }
    }

    // epilogue: D row = g*4+r, col = l15
#pragma unroll
    for (int i = 0; i < 3; ++i) {
        const int fid = wv * 3 + i;
        const int ms = fid >> 2;
        const int nf = fid & 3;
        const int pixe = pix0 + nf * 16 + l15;
        f32x4 cc = (i == 0) ? acc0 : ((i == 1) ? acc1 : acc2);
#pragma unroll
        for (int r = 0; r < 4; ++r) {
            const int row = g * 4 + r;
            if (ms < 2) {
                const int j = ms * 16 + row;
                if (j < 18)
                    off_out[((size_t)b * 18 + j) * HW_ + pixe] =
                        cc[r] + b_off[j];
            } else {
                const int j = row;
                if (j < 9) {
                    float s = cc[r] + b_mod[j];
                    mask_out[((size_t)b * 9 + j) * HW_ + pixe] =
                        2.f / (1.f + expf(-s));
                }
            }
        }
    }
}

// ---------------------------------------------------------------------------
// Deform via MFMA, NHWC-bf16 sampling: GEMM [64 o][576] x [576][64 px].
// Per tap: 4 corner gathers of bf16x8 per chalf (8 ch / 16 B each),
// off/mask prefetched one tap ahead, double-buffered B-tile -> 1 sync/step.
// ---------------------------------------------------------------------------
__global__ __launch_bounds__(256) void deform_mfma2(
    const unsigned short* __restrict__ xn,
    const float* __restrict__ off_in, const float* __restrict__ mask_in,
    const short* __restrict__ wbf,    // [64 o][9 kt][64 c]
    float* __restrict__ out)
{
    __shared__ __align__(16) unsigned short btile[2][64 * 32];

    const int tid = threadIdx.x;
    const int lane = tid & 63;
    const int wv = tid >> 6;
    const int l15 = lane & 15;
    const int g = lane >> 4;

    const int p0 = blockIdx.x * 64;
    const int b = p0 / HW_;
    const int pix0 = p0 % HW_;
    const int ho = pix0 / W_;
    const int wx0 = pix0 % W_;
    const int pix = pix0 + lane;

    const unsigned short* xnb = xn + (size_t)b * HW_ * 64;
    const int slotw = swz(lane, wv);

    f32x4 acc0 = {0.f, 0.f, 0.f, 0.f}, acc1 = acc0, acc2 = acc0, acc3 = acc0;

    // prefetch tap 0 offset/mask
    float pdy = off_in[((size_t)b * 18 + 0) * HW_ + pix];
    float pdx = off_in[((size_t)b * 18 + 1) * HW_ + pix];
    float pm  = mask_in[((size_t)b * 9 + 0) * HW_ + pix];

#pragma unroll 1
    for (int kt = 0; kt < 9; ++kt) {
        // ---- params for this tap (from prefetched data) ----
        float w00, w01, w10, w11;
        size_t a00, a01, a10, a11;
        {
            float dy = pdy, dx = pdx, m = pm;
            float py = dy + (float)(kt / 3 + ho - 1);
            float px = dx + (float)(kt % 3 + wx0 + lane - 1);
            float y0f = floorf(py), x0f = floorf(px);
            float wy1 = py - y0f, wy0 = 1.f - wy1;
            float wx1 = px - x0f, wx0w = 1.f - wx1;
            int y0 = (int)y0f, x0i = (int)x0f;
            int y1 = y0 + 1, x1 = x0i + 1;
            bool vy0 = (y0 >= 0) && (y0 < H_), vy1 = (y1 >= 0) && (y1 < H_);
            bool vx0 = (x0i >= 0) && (x0i < W_), vx1 = (x1 >= 0) && (x1 < W_);
            w00 = wy0 * wx0w * ((vy0 && vx0) ? m : 0.f);
            w01 = wy0 * wx1 * ((vy0 && vx1) ? m : 0.f);
            w10 = wy1 * wx0w * ((vy1 && vx0) ? m : 0.f);
            w11 = wy1 * wx1 * ((vy1 && vx1) ? m : 0.f);
            int y0c = min(max(y0, 0), H_ - 1), y1c = min(max(y1, 0), H_ - 1);
            int x0c = min(max(x0i, 0), W_ - 1), x1c = min(max(x1, 0), W_ - 1);
            a00 = ((size_t)(y0c * W_ + x0c)) * 64;
            a01 = ((size_t)(y0c * W_ + x1c)) * 64;
            a10 = ((size_t)(y1c * W_ + x0c)) * 64;
            a11 = ((size_t)(y1c * W_ + x1c)) * 64;
        }
        // prefetch next tap's offset/mask
        if (kt < 8) {
            pdy = off_in[((size_t)b * 18 + 2 * kt + 2) * HW_ + pix];
            pdx = off_in[((size_t)b * 18 + 2 * kt + 3) * HW_ + pix];
            pm  = mask_in[((size_t)b * 9 + kt + 1) * HW_ + pix];
        }
        // issue all 8 corner loads for both chalves
        const int cb0 = wv * 8, cb1 = 32 + wv * 8;
        bf16x8 c00 = *(const bf16x8*)(xnb + a00 + cb0);
        bf16x8 c01 = *(const bf16x8*)(xnb + a01 + cb0);
        bf16x8 c10 = *(const bf16x8*)(xnb + a10 + cb0);
        bf16x8 c11 = *(const bf16x8*)(xnb + a11 + cb0);
        bf16x8 d00 = *(const bf16x8*)(xnb + a00 + cb1);
        bf16x8 d01 = *(const bf16x8*)(xnb + a01 + cb1);
        bf16x8 d10 = *(const bf16x8*)(xnb + a10 + cb1);
        bf16x8 d11 = *(const bf16x8*)(xnb + a11 + cb1);

#pragma unroll
        for (int chalf = 0; chalf < 2; ++chalf) {
            const int step = 2 * kt + chalf;
            bf16x8 s0 = chalf ? d00 : c00;
            bf16x8 s1 = chalf ? d01 : c01;
            bf16x8 s2 = chalf ? d10 : c10;
            bf16x8 s3 = chalf ? d11 : c11;
            bf16x8 sv;
#pragma unroll
            for (int j = 0; j < 8; ++j) {
                float v = bf2f(s0[j]) * w00 + bf2f(s1[j]) * w01 +
                          bf2f(s2[j]) * w10 + bf2f(s3[j]) * w11;
                sv[j] = f2bf(v);
            }
            *(bf16x8*)&btile[chalf][lane * 32 + slotw * 8] = sv;
            bf16x8 av = *(const bf16x8*)(wbf + (size_t)(wv * 16 + l15) * 576 +
                                         step * 32 + g * 8);
            __syncthreads();
#pragma unroll
            for (int fi = 0; fi < 4; ++fi) {
                const int n2 = fi * 16 + l15;
                bf16x8 bv =
                    *(const bf16x8*)&btile[chalf][n2 * 32 + swz(n2, g) * 8];
                f32x4 cc = (fi == 0) ? acc0 : ((fi == 1) ? acc1
                            : ((fi == 2) ? acc2 : acc3));
                cc = __builtin_amdgcn_mfma_f32_16x16x32_bf16(av, bv, cc, 0, 0,
                                                             0);
                if (fi == 0) acc0 = cc; else if (fi == 1) acc1 = cc;
                else if (fi == 2) acc2 = cc; else acc3 = cc;
            }
        }
    }

    // epilogue: o = wv*16 + g*4 + r, pixel = pix0 + fi*16 + l15
#pragma unroll
    for (int fi = 0; fi < 4; ++fi) {
        f32x4 cc = (fi == 0) ? acc0 : ((fi == 1) ? acc1
                    : ((fi == 2) ? acc2 : acc3));
#pragma unroll
        for (int r = 0; r < 4; ++r) {
            const int o = wv * 16 + g * 4 + r;
            out[((size_t)b * O_ + o) * HW_ + pix0 + fi * 16 + l15] = cc[r];
        }
    }
}

// ---------------------------------------------------------------------------
// Fallback (no workspace): fully fused fp32, slow but correct.
// ---------------------------------------------------------------------------
__global__ __launch_bounds__(256) void deform_fallback(
    const float* __restrict__ x, const float* __restrict__ z,
    const float* __restrict__ w_regp,
    const float* __restrict__ w_off, const float* __restrict__ b_off,
    const float* __restrict__ w_mod, const float* __restrict__ b_mod,
    float* __restrict__ out) {
    int p = blockIdx.x * blockDim.x + threadIdx.x;
    if (p >= B_ * HW_) return;
    int wo = p % W_;
    int ho = (p / W_) % H_;
    int b  = p / HW_;
    int pix = ho * W_ + wo;

    const float* xb = x + (size_t)b * C_ * HW_;

    float accO[18], accM[9];
#pragma unroll
    for (int j = 0; j < 18; ++j) accO[j] = b_off[j];
#pragma unroll
    for (int j = 0; j < 9; ++j) accM[j] = b_mod[j];
    const float* zb = z + (size_t)b * C_ * HW_;
#pragma unroll 1
    for (int c = 0; c < C_; ++c) {
        const float* zc = zb + c * HW_;
        const float* xc = xb + c * HW_;
#pragma unroll
        for (int ky = 0; ky < 3; ++ky) {
            int iy = ho + ky - 1;
            bool vy = (iy >= 0) && (iy < H_);
#pragma unroll
            for (int kx = 0; kx < 3; ++kx) {
                int ix = wo + kx - 1;
                bool v = vy && (ix >= 0) && (ix < W_);
                int k = ky * 3 + kx;
                float zv = v ? zc[iy * W_ + ix] : 0.f;
                float xv = v ? xc[iy * W_ + ix] : 0.f;
#pragma unroll
                for (int j = 0; j < 18; ++j)
                    accO[j] = fmaf(zv, w_off[j * 576 + c * 9 + k], accO[j]);
#pragma unroll
                for (int j = 0; j < 9; ++j)
                    accM[j] = fmaf(xv, w_mod[j * 576 + c * 9 + k], accM[j]);
            }
        }
    }
    float mv[9];
#pragma unroll
    for (int j = 0; j < 9; ++j) mv[j] = 2.f / (1.f + expf(-accM[j]));

    float acc[64];
#pragma unroll
    for (int o = 0; o < 64; ++o) acc[o] = 0.f;

#pragma unroll 1
    for (int k = 0; k < 9; ++k) {
        float dy = accO[2 * k], dx = accO[2 * k + 1], m = mv[k];
        float py = dy + (float)(k / 3 + ho - 1);
        float px = dx + (float)(k % 3 + wo - 1);
        float y0f = floorf(py), x0f = floorf(px);
        float wy1 = py - y0f, wy0 = 1.f - wy1;
        float wx1 = px - x0f, wx0 = 1.f - wx1;
        int y0 = (int)y0f, x0i = (int)x0f;
        int y1 = y0 + 1, x1 = x0i + 1;
        bool vy0 = (y0 >= 0) && (y0 < H_), vy1 = (y1 >= 0) && (y1 < H_);
        bool vx0 = (x0i >= 0) && (x0i < W_), vx1 = (x1 >= 0) && (x1 < W_);
        float w00 = wy0 * wx0 * ((vy0 && vx0) ? m : 0.f);
        float w01 = wy0 * wx1 * ((vy0 && vx1) ? m : 0.f);
        float w10 = wy1 * wx0 * ((vy1 && vx0) ? m : 0.f);
        float w11 = wy1 * wx1 * ((vy1 && vx1) ? m : 0.f);
        int y0c = min(max(y0, 0), H_ - 1), y1c = min(max(y1, 0), H_ - 1);
        int x0c = min(max(x0i, 0), W_ - 1), x1c = min(max(x1, 0), W_ - 1);
        int i00 = y0c * W_ + x0c, i01 = y0c * W_ + x1c;
        int i10 = y1c * W_ + x0c, i11 = y1c * W_ + x1c;
#pragma unroll 1
        for (int c = 0; c < C_; ++c) {
            const float* xc = xb + c * HW_;
            float val = xc[i00] * w00 + xc[i01] * w01 + xc[i10] * w10 +
                        xc[i11] * w11;
            const float* wr = w_regp + c * 9 + k;
#pragma unroll
            for (int o = 0; o < 64; ++o)
                acc[o] = fmaf(val, wr[o * 576], acc[o]);
        }
    }
    float* ob = out + (size_t)b * O_ * HW_ + pix;
#pragma unroll
    for (int o = 0; o < 64; ++o) ob[o * HW_] = acc[o];
}

// ---------------------------------------------------------------------------
extern "C" void kernel_launch(void* const* d_in, const int* in_sizes, int n_in,
                              void* d_out, int out_size, void* d_ws,
                              size_t ws_size, hipStream_t stream) {
    const float* x     = (const float*)d_in[0];
    const float* z     = (const float*)d_in[1];
    const float* w_off = (const float*)d_in[2];
    const float* b_off = (const float*)d_in[3];
    const float* w_mod = (const float*)d_in[4];
    const float* b_mod = (const float*)d_in[5];
    const float* w_reg = (const float*)d_in[6];
    float* out = (float*)d_out;

    // ws layout (bytes):
    //   wbf  73728 | wzbf 36864 | wxbf 18432      -> 129024
    //   xn   16777216 (NHWC bf16)
    //   zn   16777216
    //   off_buf  9437184 (f32)
    //   mask_buf 4718592 (f32)
    const size_t need = 129024 + 2 * 16777216ull + 9437184 + 4718592;

    const int npix = B_ * HW_;   // 131072
    const int ntile = npix / 64; // 2048

    if (ws_size >= need) {
        short* wbf  = (short*)d_ws;
        short* wzbf = wbf + 36864;
        short* wxbf = wzbf + 18432;
        unsigned short* xn = (unsigned short*)((char*)d_ws + 129024);
        unsigned short* zn = xn + 8388608;
        float* off_buf  = (float*)((char*)d_ws + 129024 + 2 * 16777216ull);
        float* mask_buf = off_buf + (size_t)B_ * 18 * HW_;

        prep_weights<<<144, 256, 0, stream>>>(w_off, w_mod, w_reg, wbf, wzbf,
                                              wxbf);
        to_nhwc<<<2048, 256, 0, stream>>>(x, z, xn, zn);
        conv_mfma2<<<ntile, 256, 0, stream>>>(zn, xn, wzbf, wxbf, b_off, b_mod,
                                              off_buf, mask_buf);
        deform_mfma2<<<ntile, 256, 0, stream>>>(xn, off_buf, mask_buf, wbf,
                                                out);
    } else {
        deform_fallback<<<(npix + 255) / 256, 256, 0, stream>>>(
            x, z, w_reg, w_off, b_off, w_mod, b_mod, out);
    }
}